// Round 12
// baseline (127.975 us; speedup 1.0000x reference)
//
#include <hip/hip_runtime.h>

#define N_NODES 50000
#define N_EDGES 800000
#define N_TOT   850000   // edges + self-loops
#define SD 128
#define HD 256
#define OD 41
#define ODP 48
#define NG 512
#define NB 128           // dst-range buckets
#define NPB 391          // nodes per bucket (128*391 = 50048 >= 50000)
#define BCAP 8192        // records per bucket capacity

typedef __attribute__((ext_vector_type(8))) short bh8;   // 8 bf16 = 4 VGPR (MFMA A/B frag)
typedef __attribute__((ext_vector_type(4))) float f4;    // MFMA C/D frag
typedef unsigned long long u64;

__device__ inline unsigned short f2bf(float x) {         // RNE float->bf16
  unsigned u = __float_as_uint(x);
  unsigned r = u + 0x7fff + ((u >> 16) & 1);
  return (unsigned short)(r >> 16);
}
__device__ inline float bf2f(unsigned short s) {
  return __uint_as_float(((unsigned)s) << 16);
}
__device__ inline float bflo(unsigned e) { return __uint_as_float(e << 16); }
__device__ inline float bfhi(unsigned e) { return __uint_as_float(e & 0xffff0000u); }
__device__ inline unsigned pk2(float lo, float hi) {
  return (unsigned)f2bf(lo) | ((unsigned)f2bf(hi) << 16);
}

// final 8B edge record: [63:48] norm(bf16), [26:16] xid, [15:0] src
__device__ inline unsigned rec_xid(u64 r)  { return ((unsigned)r) >> 16; }
__device__ inline unsigned rec_src(u64 r)  { return ((unsigned)r) & 0xFFFFu; }
__device__ inline float    rec_nrm(u64 r)  { return __uint_as_float((unsigned)(r >> 32) & 0xFFFF0000u); }

// init: emb/W1/W2 conversions + zero curB + zero out + gstart, one launch
__global__ __launch_bounds__(256) void init_kernel(const float* __restrict__ emb,
    const float* __restrict__ W1, const float* __restrict__ W2,
    const int* __restrict__ batch,
    unsigned short* __restrict__ embb, unsigned short* __restrict__ w1f,
    unsigned short* __restrict__ w2f, float4* __restrict__ curB4,
    float4* __restrict__ out4, int* __restrict__ gstart) {
  int tid = blockIdx.x * 256 + threadIdx.x;
  if (tid < 1340 * SD) { embb[tid] = f2bf(emb[tid]); return; }
  int u = tid - 1340 * SD;
  if (u < 4096) {           // W1f[frag=ks*16+cf][lane][j]
    int lane = u & 63, frag = u >> 6;
    int ks = frag >> 4, cf = frag & 15;
    int col = cf * 16 + (lane & 15);
    #pragma unroll
    for (int j = 0; j < 8; ++j) {
      int k = ks * 32 + ((lane >> 4) << 3) + j;
      w1f[u * 8 + j] = f2bf(W1[k * HD + col]);
    }
    return;
  }
  u -= 4096;
  if (u < 1536) {           // W2f[frag=ks*3+cf][lane][j], zero-pad cols 41..47
    int lane = u & 63, frag = u >> 6;
    int ks = frag / 3, cf = frag % 3;
    int col = cf * 16 + (lane & 15);
    #pragma unroll
    for (int j = 0; j < 8; ++j) {
      int k = ks * 32 + ((lane >> 4) << 3) + j;
      w2f[u * 8 + j] = (col < OD) ? f2bf(W2[k * OD + col]) : (unsigned short)0;
    }
    return;
  }
  u -= 1536;
  float4 z = make_float4(0.f, 0.f, 0.f, 0.f);
  if (u < 32) { curB4[u] = z; return; }
  u -= 32;
  if (u < 5248) { out4[u] = z; return; }
  u -= 5248;
  if (u < N_NODES) {        // graph-start boundaries from sorted batch
    int i = u;
    if (i == 0) {
      for (int g = 0; g <= batch[0]; ++g) gstart[g] = 0;
    } else {
      int bp = batch[i - 1], bn = batch[i];
      for (int g = bp + 1; g <= bn; ++g) gstart[g] = i;
    }
    if (i == N_NODES - 1) {
      for (int g = batch[i] + 1; g <= NG; ++g) gstart[g] = N_NODES;
    }
  }
}

// passA: bin edges (+self-loops) into NB dst-range buckets.
// staged record: [47:32] xid, [31:16] dst, [15:0] src
__global__ __launch_bounds__(256) void passA_kernel(const int* __restrict__ ei,
    const int* __restrict__ x_ids, int* __restrict__ curB, u64* __restrict__ stage) {
  __shared__ int lcur[NB];
  __shared__ int base[NB];
  int t = threadIdx.x;
  if (t < NB) lcur[t] = 0;
  __syncthreads();
  u64 pay[16];
  int loc[16];
  int e0 = blockIdx.x * 4096;
  #pragma unroll
  for (int j = 0; j < 16; ++j) {
    int e = e0 + j * 256 + t;
    loc[j] = -1;
    if (e < N_TOT) {
      int s, d;
      if (e < N_EDGES) { s = ei[e]; d = ei[N_EDGES + e]; }
      else             { s = d = e - N_EDGES; }
      int b = d / NPB;
      int lofs = atomicAdd(&lcur[b], 1);
      loc[j] = (b << 13) | lofs;
      pay[j] = ((u64)(unsigned)x_ids[s] << 32) | ((u64)(unsigned)d << 16) | (u64)(unsigned)s;
    }
  }
  __syncthreads();
  if (t < NB) base[t] = atomicAdd(&curB[t], lcur[t]);
  __syncthreads();
  #pragma unroll
  for (int j = 0; j < 16; ++j) {
    if (loc[j] >= 0) {
      int b = loc[j] >> 13, lofs = loc[j] & 8191;
      stage[(size_t)b * BCAP + base[b] + lofs] = pay[j];
    }
  }
}

// countscan: per bucket, count per-node records, local exclusive scan,
// bucket base from in-block scan of curB -> off, dinv.
__global__ __launch_bounds__(256) void countscan_kernel(const int* __restrict__ curB,
    const u64* __restrict__ stage, int* __restrict__ off, float* __restrict__ dinv) {
  __shared__ int cl[NPB];
  __shared__ int sc[512];
  __shared__ int bs[NB];
  int t = threadIdx.x, k = blockIdx.x;
  for (int l = t; l < NPB; l += 256) cl[l] = 0;
  if (t < NB) bs[t] = curB[t];
  __syncthreads();
  // bucket-base scan over 128 totals (inclusive)
  for (int s = 1; s < NB; s <<= 1) {
    int a = (t < NB && t >= s) ? bs[t - s] : 0;
    __syncthreads();
    if (t < NB) bs[t] += a;
    __syncthreads();
  }
  int base = (k == 0) ? 0 : bs[k - 1];
  // count
  int nbk = curB[k];
  const u64* st = stage + (size_t)k * BCAP;
  for (int i = t; i < nbk; i += 256) {
    int d = (int)((st[i] >> 16) & 0xFFFFu);
    atomicAdd(&cl[d - k * NPB], 1);
  }
  __syncthreads();
  // local inclusive scan of 391 counts (padded to 512, 2 elems/thread)
  sc[t]       = (t < NPB)       ? cl[t]       : 0;
  sc[t + 256] = (t + 256 < NPB) ? cl[t + 256] : 0;
  __syncthreads();
  for (int s = 1; s < 512; s <<= 1) {
    int a0 = (t >= s) ? sc[t - s] : 0;
    int a1 = (t + 256 >= s) ? sc[t + 256 - s] : 0;
    __syncthreads();
    sc[t] += a0; sc[t + 256] += a1;
    __syncthreads();
  }
  int n0 = k * NPB;
  int nn = (n0 + NPB <= N_NODES) ? NPB : (N_NODES - n0);
  for (int l = t; l < nn; l += 256) {
    int v = cl[l];                        // = deg + 1 (self-loop staged)
    off[n0 + l] = base + sc[l] - v;       // global exclusive offset
    dinv[n0 + l] = rsqrtf((float)v);
  }
  if (k == 0 && t == 0) off[N_NODES] = N_TOT;
}

// passB: scatter bucket staging -> final CSR rec (writes confined to bucket window)
__global__ __launch_bounds__(256) void passB_kernel(const int* __restrict__ curB,
    const u64* __restrict__ stage, const int* __restrict__ off,
    const float* __restrict__ dinv, u64* __restrict__ rec) {
  __shared__ int lcur[NPB];
  __shared__ int loff[NPB];
  int t = threadIdx.x, k = blockIdx.x;
  int n0 = k * NPB;
  int nn = (n0 + NPB <= N_NODES) ? NPB : (N_NODES - n0);
  for (int l = t; l < nn; l += 256) { lcur[l] = 0; loff[l] = off[n0 + l]; }
  __syncthreads();
  int nbk = curB[k];
  const u64* st = stage + (size_t)k * BCAP;
  for (int i = t; i < nbk; i += 256) {
    u64 r = st[i];
    int s   = (int)(r & 0xFFFFu);
    int d   = (int)((r >> 16) & 0xFFFFu);
    int xid = (int)((r >> 32) & 0xFFFFu);
    float nrm = dinv[s] * dinv[d];          // self-loop s==d -> dinv^2, same formula
    int ld = d - n0;
    int p = loff[ld] + atomicAdd(&lcur[ld], 1);
    rec[p] = ((u64)f2bf(nrm) << 48) | ((u64)(unsigned)xid << 16) | (u64)(unsigned)s;
  }
}

// FUSED layer 1: gather-aggregate (CSR x emb) directly into swizzled LDS tile,
// then h2b = bf16( relu(tile@W1+b1) @ W2 ).  64-row tile, 4 waves x 16 nodes.
__global__ __launch_bounds__(256) void fused12_kernel(const int* __restrict__ off,
    const u64* __restrict__ rec, const uint4* __restrict__ emb16,
    const bh8* __restrict__ w1f, const float* __restrict__ b1,
    const bh8* __restrict__ w2f, unsigned short* __restrict__ h2b) {
  __shared__ char raw[32768];   // phase1: agg tile 64x128 bf16 [0:16K]; phase3: y1 tile 64x256 bf16
  int t = threadIdx.x, lane = t & 63, wave = t >> 6;
  int row0 = blockIdx.x * 64;
  int eslot = lane >> 4, fgrp = lane & 15;

  // ---- phase 1: per-wave gather-aggregate of 16 nodes into LDS ----
  for (int ln = 0; ln < 16; ++ln) {
    int r = wave * 16 + ln;             // tile row
    int node = row0 + r;
    float a[8];
    #pragma unroll
    for (int j = 0; j < 8; ++j) a[j] = 0.f;
    if (node < N_NODES) {
      int beg = off[node], end = off[node + 1];
      int i = beg;
      for (; i + 16 <= end; i += 16) {  // 4 groups of 4 edges in flight
        u64 r0 = rec[i + eslot];
        u64 r1 = rec[i + 4 + eslot];
        u64 r2 = rec[i + 8 + eslot];
        u64 r3 = rec[i + 12 + eslot];
        uint4 v0 = emb16[rec_xid(r0) * 16 + fgrp];
        uint4 v1 = emb16[rec_xid(r1) * 16 + fgrp];
        uint4 v2 = emb16[rec_xid(r2) * 16 + fgrp];
        uint4 v3 = emb16[rec_xid(r3) * 16 + fgrp];
        float n0 = rec_nrm(r0), n1 = rec_nrm(r1), n2 = rec_nrm(r2), n3 = rec_nrm(r3);
        a[0] += n0 * bflo(v0.x); a[1] += n0 * bfhi(v0.x);
        a[2] += n0 * bflo(v0.y); a[3] += n0 * bfhi(v0.y);
        a[4] += n0 * bflo(v0.z); a[5] += n0 * bfhi(v0.z);
        a[6] += n0 * bflo(v0.w); a[7] += n0 * bfhi(v0.w);
        a[0] += n1 * bflo(v1.x); a[1] += n1 * bfhi(v1.x);
        a[2] += n1 * bflo(v1.y); a[3] += n1 * bfhi(v1.y);
        a[4] += n1 * bflo(v1.z); a[5] += n1 * bfhi(v1.z);
        a[6] += n1 * bflo(v1.w); a[7] += n1 * bfhi(v1.w);
        a[0] += n2 * bflo(v2.x); a[1] += n2 * bfhi(v2.x);
        a[2] += n2 * bflo(v2.y); a[3] += n2 * bfhi(v2.y);
        a[4] += n2 * bflo(v2.z); a[5] += n2 * bfhi(v2.z);
        a[6] += n2 * bflo(v2.w); a[7] += n2 * bfhi(v2.w);
        a[0] += n3 * bflo(v3.x); a[1] += n3 * bfhi(v3.x);
        a[2] += n3 * bflo(v3.y); a[3] += n3 * bfhi(v3.y);
        a[4] += n3 * bflo(v3.z); a[5] += n3 * bfhi(v3.z);
        a[6] += n3 * bflo(v3.w); a[7] += n3 * bfhi(v3.w);
      }
      for (; i + 8 <= end; i += 8) {    // 2 groups of 4 edges
        u64 rA = rec[i + eslot];
        u64 rB = rec[i + 4 + eslot];
        uint4 vA = emb16[rec_xid(rA) * 16 + fgrp];
        uint4 vB = emb16[rec_xid(rB) * 16 + fgrp];
        float nA = rec_nrm(rA), nB = rec_nrm(rB);
        a[0] += nA * bflo(vA.x); a[1] += nA * bfhi(vA.x);
        a[2] += nA * bflo(vA.y); a[3] += nA * bfhi(vA.y);
        a[4] += nA * bflo(vA.z); a[5] += nA * bfhi(vA.z);
        a[6] += nA * bflo(vA.w); a[7] += nA * bfhi(vA.w);
        a[0] += nB * bflo(vB.x); a[1] += nB * bfhi(vB.x);
        a[2] += nB * bflo(vB.y); a[3] += nB * bfhi(vB.y);
        a[4] += nB * bflo(vB.z); a[5] += nB * bfhi(vB.z);
        a[6] += nB * bflo(vB.w); a[7] += nB * bfhi(vB.w);
      }
      for (; i < end; i += 4) {         // tail groups (masked)
        int idx = i + eslot;
        bool val = idx < end;
        u64 r4 = rec[val ? idx : (end - 1)];
        uint4 v = emb16[rec_xid(r4) * 16 + fgrp];
        float n = val ? rec_nrm(r4) : 0.f;
        a[0] += n * bflo(v.x); a[1] += n * bfhi(v.x);
        a[2] += n * bflo(v.y); a[3] += n * bfhi(v.y);
        a[4] += n * bflo(v.z); a[5] += n * bfhi(v.z);
        a[6] += n * bflo(v.w); a[7] += n * bfhi(v.w);
      }
    }
    #pragma unroll
    for (int j = 0; j < 8; ++j) {       // reduce across eslots (lanes ^16, ^32)
      a[j] += __shfl_xor(a[j], 16);
      a[j] += __shfl_xor(a[j], 32);
    }
    if (lane < 16) {                    // write row r, cols fgrp*8..+7 (swizzled)
      uint4 o;
      o.x = pk2(a[0], a[1]); o.y = pk2(a[2], a[3]);
      o.z = pk2(a[4], a[5]); o.w = pk2(a[6], a[7]);
      *(uint4*)(raw + ((r * 256 + fgrp * 16) ^ ((r & 15) << 4))) = o;
    }
  }

  // ---- phase 2: y1 = relu(tile @ W1 + b1) via MFMA ----
  bh8 bf1[4][4];
  #pragma unroll
  for (int cf = 0; cf < 4; ++cf)
    #pragma unroll
    for (int ks = 0; ks < 4; ++ks)
      bf1[cf][ks] = w1f[(ks * 16 + wave * 4 + cf) * 64 + lane];
  f4 acc[4][4];
  #pragma unroll
  for (int rf = 0; rf < 4; ++rf)
    #pragma unroll
    for (int cf = 0; cf < 4; ++cf)
      acc[rf][cf] = (f4){0.f, 0.f, 0.f, 0.f};
  __syncthreads();
  #pragma unroll
  for (int ks = 0; ks < 4; ++ks) {
    bh8 a[4];
    #pragma unroll
    for (int rf = 0; rf < 4; ++rf) {
      int r = rf * 16 + (lane & 15);
      int byte = (r * 256 + ks * 64 + ((lane >> 4) << 4)) ^ ((r & 15) << 4);
      a[rf] = *(const bh8*)(raw + byte);
    }
    #pragma unroll
    for (int rf = 0; rf < 4; ++rf)
      #pragma unroll
      for (int cf = 0; cf < 4; ++cf)
        acc[rf][cf] = __builtin_amdgcn_mfma_f32_16x16x32_bf16(a[rf], bf1[cf][ks], acc[rf][cf], 0, 0, 0);
  }
  __syncthreads();    // all tile reads complete before overwrite
  // bias+relu, write bf16 y1 tile into LDS (row stride 512B, same swizzle)
  #pragma unroll
  for (int cf = 0; cf < 4; ++cf) {
    int col = wave * 64 + cf * 16 + (lane & 15);
    float bias = b1[col];
    #pragma unroll
    for (int rf = 0; rf < 4; ++rf)
      #pragma unroll
      for (int j = 0; j < 4; ++j) {
        int r = rf * 16 + ((lane >> 4) << 2) + j;
        unsigned short v = f2bf(fmaxf(acc[rf][cf][j] + bias, 0.f));
        *(unsigned short*)(raw + ((r * 512 + col * 2) ^ ((r & 15) << 4))) = v;
      }
  }
  // ---- phase 3: h2b = y1 @ W2 via MFMA ----
  bh8 bf2[3][8];
  #pragma unroll
  for (int cf = 0; cf < 3; ++cf)
    #pragma unroll
    for (int ks = 0; ks < 8; ++ks)
      bf2[cf][ks] = w2f[(ks * 3 + cf) * 64 + lane];
  f4 acc2[3];
  #pragma unroll
  for (int cf = 0; cf < 3; ++cf) acc2[cf] = (f4){0.f, 0.f, 0.f, 0.f};
  __syncthreads();
  int r2 = wave * 16 + (lane & 15);
  #pragma unroll
  for (int ks = 0; ks < 8; ++ks) {
    int byte = (r2 * 512 + ks * 64 + ((lane >> 4) << 4)) ^ ((r2 & 15) << 4);
    bh8 a = *(const bh8*)(raw + byte);
    #pragma unroll
    for (int cf = 0; cf < 3; ++cf)
      acc2[cf] = __builtin_amdgcn_mfma_f32_16x16x32_bf16(a, bf2[cf][ks], acc2[cf], 0, 0, 0);
  }
  #pragma unroll
  for (int cf = 0; cf < 3; ++cf) {
    int col = cf * 16 + (lane & 15);
    #pragma unroll
    for (int j = 0; j < 4; ++j) {
      int rg = row0 + wave * 16 + ((lane >> 4) << 2) + j;
      if (rg < N_NODES)
        h2b[(size_t)rg * ODP + col] = f2bf(acc2[cf][j]);
    }
  }
}

// fused layer-2 aggregation + graph pooling.
// 10 edges per gather instruction: lane = (eslot 0..9, fgrp 0..5), dwordx4/lane;
// 20-edge (2-group) leading loop; LDS reduce across waves+eslots.
__global__ __launch_bounds__(256) void pool2_kernel(const int* __restrict__ gstart,
    const int* __restrict__ off, const u64* __restrict__ rec,
    const unsigned short* __restrict__ h2b, const float* __restrict__ b2,
    float* __restrict__ out) {
  __shared__ float red[4][60][8];   // 30.7 KB
  int g = blockIdx.x >> 3, c = blockIdx.x & 7;
  int t = threadIdx.x, lane = t & 63, wv = t >> 6;
  int n0 = gstart[g], n1 = gstart[g + 1];
  int e0 = off[n0], e1 = off[n1];
  int len = e1 - e0;
  int c0 = e0 + ((len * c) >> 3);
  int c1 = e0 + ((len * (c + 1)) >> 3);
  int clen = c1 - c0;
  int w0 = c0 + ((clen * wv) >> 2);
  int w1 = c0 + ((clen * (wv + 1)) >> 2);
  bool live = lane < 60;
  int eslot = live ? lane / 6 : 0;      // 0..9
  int fgrp  = live ? lane - (lane / 6) * 6 : 0;   // 0..5 (feats fgrp*8..+7)
  float a[8];
  #pragma unroll
  for (int j = 0; j < 8; ++j) a[j] = 0.f;
  int i = w0;
  for (; i + 20 <= w1; i += 20) {       // 20 edges (2 groups) in flight
    u64 rA = rec[i + eslot];
    u64 rB = rec[i + 10 + eslot];
    uint4 vA = *(const uint4*)(h2b + (size_t)rec_src(rA) * ODP + fgrp * 8);
    uint4 vB = *(const uint4*)(h2b + (size_t)rec_src(rB) * ODP + fgrp * 8);
    float nA = live ? rec_nrm(rA) : 0.f;
    float nB = live ? rec_nrm(rB) : 0.f;
    a[0] += nA * bflo(vA.x); a[1] += nA * bfhi(vA.x);
    a[2] += nA * bflo(vA.y); a[3] += nA * bfhi(vA.y);
    a[4] += nA * bflo(vA.z); a[5] += nA * bfhi(vA.z);
    a[6] += nA * bflo(vA.w); a[7] += nA * bfhi(vA.w);
    a[0] += nB * bflo(vB.x); a[1] += nB * bfhi(vB.x);
    a[2] += nB * bflo(vB.y); a[3] += nB * bfhi(vB.y);
    a[4] += nB * bflo(vB.z); a[5] += nB * bfhi(vB.z);
    a[6] += nB * bflo(vB.w); a[7] += nB * bfhi(vB.w);
  }
  for (; i + 10 <= w1; i += 10) {
    u64 r = rec[i + eslot];
    uint4 v = *(const uint4*)(h2b + (size_t)rec_src(r) * ODP + fgrp * 8);
    float n = live ? rec_nrm(r) : 0.f;
    a[0] += n * bflo(v.x); a[1] += n * bfhi(v.x);
    a[2] += n * bflo(v.y); a[3] += n * bfhi(v.y);
    a[4] += n * bflo(v.z); a[5] += n * bfhi(v.z);
    a[6] += n * bflo(v.w); a[7] += n * bfhi(v.w);
  }
  if (i < w1) {                         // one masked tail group
    int idx = i + eslot;
    bool val = live && idx < w1;
    u64 r = rec[val ? idx : w0];
    uint4 v = *(const uint4*)(h2b + (size_t)rec_src(r) * ODP + fgrp * 8);
    float n = val ? rec_nrm(r) : 0.f;
    a[0] += n * bflo(v.x); a[1] += n * bfhi(v.x);
    a[2] += n * bflo(v.y); a[3] += n * bfhi(v.y);
    a[4] += n * bflo(v.z); a[5] += n * bfhi(v.z);
    a[6] += n * bflo(v.w); a[7] += n * bfhi(v.w);
  }
  if (live) {
    #pragma unroll
    for (int j = 0; j < 8; ++j) red[wv][lane][j] = a[j];
  }
  __syncthreads();
  if (t < 48) {                         // feature f = t
    int fg = t >> 3, j = t & 7;
    float s = 0.f;
    #pragma unroll
    for (int w = 0; w < 4; ++w)
      #pragma unroll
      for (int e = 0; e < 10; ++e)
        s += red[w][e * 6 + fg][j];
    if (t < OD) {
      if (c == 0) s += (float)(n1 - n0) * b2[t];
      unsafeAtomicAdd(&out[g * OD + t], s);
    }
  }
}

extern "C" void kernel_launch(void* const* d_in, const int* in_sizes, int n_in,
                              void* d_out, int out_size, void* d_ws, size_t ws_size,
                              hipStream_t stream) {
  const int*   x_ids = (const int*)d_in[0];
  const int*   ei    = (const int*)d_in[1];
  const int*   batch = (const int*)d_in[2];
  const float* emb   = (const float*)d_in[3];
  const float* W1    = (const float*)d_in[4];
  const float* b1    = (const float*)d_in[5];
  const float* W2    = (const float*)d_in[6];
  const float* b2    = (const float*)d_in[7];
  float* out = (float*)d_out;
  char* ws = (char*)d_ws;

  // workspace layout (bytes)
  int*            curB   = (int*)           (ws + 0);          // 512 B bucket cursors
  float*          dinv   = (float*)         (ws + 4096);       // 200 KB
  int*            off    = (int*)           (ws + 208896);     // 200 KB (+4)
  int*            gstart = (int*)           (ws + 413696);     // 2052 B
  unsigned short* embb   = (unsigned short*)(ws + 1048576);    // 343 KB bf16 emb
  unsigned short* w1f    = (unsigned short*)(ws + 1441792);    // 64 KB frag-linear
  unsigned short* w2f    = (unsigned short*)(ws + 1507328);    // 24 KB frag-linear
  u64*            rec    = (u64*)           (ws + 2097152);    // 6.8 MB final CSR records
  u64*            stage  = (u64*)           (ws + 9437184);    // 8.4 MB bucket staging
  unsigned short* h2b    = (unsigned short*)(ws + 18874368);   // 4.8 MB

  init_kernel <<<908, 256, 0, stream>>>(emb, W1, W2, batch, embb, w1f, w2f,
                                        (float4*)curB, (float4*)out, gstart);
  passA_kernel<<<208, 256, 0, stream>>>(ei, x_ids, curB, stage);
  countscan_kernel<<<NB, 256, 0, stream>>>(curB, stage, off, dinv);
  passB_kernel<<<NB,  256, 0, stream>>>(curB, stage, off, dinv, rec);

  fused12_kernel<<<782, 256, 0, stream>>>(off, rec, (const uint4*)embb,
                                          (const bh8*)w1f, b1, (const bh8*)w2f, h2b);
  pool2_kernel<<<4096, 256, 0, stream>>>(gstart, off, rec, h2b, b2, out);
}

// Round 13
// 101.605 us; speedup vs baseline: 1.2595x; 1.2595x over previous
//
#include <hip/hip_runtime.h>

#define N_NODES 50000
#define N_EDGES 800000
#define N_TOT   850000   // edges + self-loops
#define SD 128
#define HD 256
#define OD 41
#define ODP 48
#define NG 512
#define NB 128           // dst-range buckets
#define NPB 391          // nodes per bucket (128*391 = 50048 >= 50000)
#define BCAP 8192        // records per bucket capacity

typedef __attribute__((ext_vector_type(8))) short bh8;   // 8 bf16 = 4 VGPR (MFMA A/B frag)
typedef __attribute__((ext_vector_type(4))) float f4;    // MFMA C/D frag
typedef unsigned long long u64;

__device__ inline unsigned short f2bf(float x) {         // RNE float->bf16
  unsigned u = __float_as_uint(x);
  unsigned r = u + 0x7fff + ((u >> 16) & 1);
  return (unsigned short)(r >> 16);
}
__device__ inline float bf2f(unsigned short s) {
  return __uint_as_float(((unsigned)s) << 16);
}
__device__ inline float bflo(unsigned e) { return __uint_as_float(e << 16); }
__device__ inline float bfhi(unsigned e) { return __uint_as_float(e & 0xffff0000u); }
__device__ inline unsigned pk2(float lo, float hi) {
  return (unsigned)f2bf(lo) | ((unsigned)f2bf(hi) << 16);
}

// final 8B edge record: [63:48] norm(bf16), [26:16] xid, [15:0] src
__device__ inline unsigned rec_xid(u64 r)  { return ((unsigned)r) >> 16; }
__device__ inline unsigned rec_src(u64 r)  { return ((unsigned)r) & 0xFFFFu; }
__device__ inline float    rec_nrm(u64 r)  { return __uint_as_float((unsigned)(r >> 32) & 0xFFFF0000u); }

// init: emb/W1/W2 conversions + zero curB + zero out + gstart, one launch
__global__ __launch_bounds__(256) void init_kernel(const float* __restrict__ emb,
    const float* __restrict__ W1, const float* __restrict__ W2,
    const int* __restrict__ batch,
    unsigned short* __restrict__ embb, unsigned short* __restrict__ w1f,
    unsigned short* __restrict__ w2f, float4* __restrict__ curB4,
    float4* __restrict__ out4, int* __restrict__ gstart) {
  int tid = blockIdx.x * 256 + threadIdx.x;
  if (tid < 1340 * SD) { embb[tid] = f2bf(emb[tid]); return; }
  int u = tid - 1340 * SD;
  if (u < 4096) {           // W1f[frag=ks*16+cf][lane][j]
    int lane = u & 63, frag = u >> 6;
    int ks = frag >> 4, cf = frag & 15;
    int col = cf * 16 + (lane & 15);
    #pragma unroll
    for (int j = 0; j < 8; ++j) {
      int k = ks * 32 + ((lane >> 4) << 3) + j;
      w1f[u * 8 + j] = f2bf(W1[k * HD + col]);
    }
    return;
  }
  u -= 4096;
  if (u < 1536) {           // W2f[frag=ks*3+cf][lane][j], zero-pad cols 41..47
    int lane = u & 63, frag = u >> 6;
    int ks = frag / 3, cf = frag % 3;
    int col = cf * 16 + (lane & 15);
    #pragma unroll
    for (int j = 0; j < 8; ++j) {
      int k = ks * 32 + ((lane >> 4) << 3) + j;
      w2f[u * 8 + j] = (col < OD) ? f2bf(W2[k * OD + col]) : (unsigned short)0;
    }
    return;
  }
  u -= 1536;
  float4 z = make_float4(0.f, 0.f, 0.f, 0.f);
  if (u < 32) { curB4[u] = z; return; }
  u -= 32;
  if (u < 5248) { out4[u] = z; return; }
  u -= 5248;
  if (u < N_NODES) {        // graph-start boundaries from sorted batch
    int i = u;
    if (i == 0) {
      for (int g = 0; g <= batch[0]; ++g) gstart[g] = 0;
    } else {
      int bp = batch[i - 1], bn = batch[i];
      for (int g = bp + 1; g <= bn; ++g) gstart[g] = i;
    }
    if (i == N_NODES - 1) {
      for (int g = batch[i] + 1; g <= NG; ++g) gstart[g] = N_NODES;
    }
  }
}

// passA: bin edges (+self-loops) into NB dst-range buckets.
// staged record: [47:32] xid, [31:16] dst, [15:0] src
__global__ __launch_bounds__(256) void passA_kernel(const int* __restrict__ ei,
    const int* __restrict__ x_ids, int* __restrict__ curB, u64* __restrict__ stage) {
  __shared__ int lcur[NB];
  __shared__ int base[NB];
  int t = threadIdx.x;
  if (t < NB) lcur[t] = 0;
  __syncthreads();
  u64 pay[16];
  int loc[16];
  int e0 = blockIdx.x * 4096;
  #pragma unroll
  for (int j = 0; j < 16; ++j) {
    int e = e0 + j * 256 + t;
    loc[j] = -1;
    if (e < N_TOT) {
      int s, d;
      if (e < N_EDGES) { s = ei[e]; d = ei[N_EDGES + e]; }
      else             { s = d = e - N_EDGES; }
      int b = d / NPB;
      int lofs = atomicAdd(&lcur[b], 1);
      loc[j] = (b << 13) | lofs;
      pay[j] = ((u64)(unsigned)x_ids[s] << 32) | ((u64)(unsigned)d << 16) | (u64)(unsigned)s;
    }
  }
  __syncthreads();
  if (t < NB) base[t] = atomicAdd(&curB[t], lcur[t]);
  __syncthreads();
  #pragma unroll
  for (int j = 0; j < 16; ++j) {
    if (loc[j] >= 0) {
      int b = loc[j] >> 13, lofs = loc[j] & 8191;
      stage[(size_t)b * BCAP + base[b] + lofs] = pay[j];
    }
  }
}

// countscan: per bucket, count per-node records, local exclusive scan,
// bucket base from in-block scan of curB -> off, dinv.
__global__ __launch_bounds__(256) void countscan_kernel(const int* __restrict__ curB,
    const u64* __restrict__ stage, int* __restrict__ off, float* __restrict__ dinv) {
  __shared__ int cl[NPB];
  __shared__ int sc[512];
  __shared__ int bs[NB];
  int t = threadIdx.x, k = blockIdx.x;
  for (int l = t; l < NPB; l += 256) cl[l] = 0;
  if (t < NB) bs[t] = curB[t];
  __syncthreads();
  // bucket-base scan over 128 totals (inclusive)
  for (int s = 1; s < NB; s <<= 1) {
    int a = (t < NB && t >= s) ? bs[t - s] : 0;
    __syncthreads();
    if (t < NB) bs[t] += a;
    __syncthreads();
  }
  int base = (k == 0) ? 0 : bs[k - 1];
  // count
  int nbk = curB[k];
  const u64* st = stage + (size_t)k * BCAP;
  for (int i = t; i < nbk; i += 256) {
    int d = (int)((st[i] >> 16) & 0xFFFFu);
    atomicAdd(&cl[d - k * NPB], 1);
  }
  __syncthreads();
  // local inclusive scan of 391 counts (padded to 512, 2 elems/thread)
  sc[t]       = (t < NPB)       ? cl[t]       : 0;
  sc[t + 256] = (t + 256 < NPB) ? cl[t + 256] : 0;
  __syncthreads();
  for (int s = 1; s < 512; s <<= 1) {
    int a0 = (t >= s) ? sc[t - s] : 0;
    int a1 = (t + 256 >= s) ? sc[t + 256 - s] : 0;
    __syncthreads();
    sc[t] += a0; sc[t + 256] += a1;
    __syncthreads();
  }
  int n0 = k * NPB;
  int nn = (n0 + NPB <= N_NODES) ? NPB : (N_NODES - n0);
  for (int l = t; l < nn; l += 256) {
    int v = cl[l];                        // = deg + 1 (self-loop staged)
    off[n0 + l] = base + sc[l] - v;       // global exclusive offset
    dinv[n0 + l] = rsqrtf((float)v);
  }
  if (k == 0 && t == 0) off[N_NODES] = N_TOT;
}

// passB: scatter bucket staging -> final CSR rec (writes confined to bucket window)
__global__ __launch_bounds__(256) void passB_kernel(const int* __restrict__ curB,
    const u64* __restrict__ stage, const int* __restrict__ off,
    const float* __restrict__ dinv, u64* __restrict__ rec) {
  __shared__ int lcur[NPB];
  __shared__ int loff[NPB];
  int t = threadIdx.x, k = blockIdx.x;
  int n0 = k * NPB;
  int nn = (n0 + NPB <= N_NODES) ? NPB : (N_NODES - n0);
  for (int l = t; l < nn; l += 256) { lcur[l] = 0; loff[l] = off[n0 + l]; }
  __syncthreads();
  int nbk = curB[k];
  const u64* st = stage + (size_t)k * BCAP;
  for (int i = t; i < nbk; i += 256) {
    u64 r = st[i];
    int s   = (int)(r & 0xFFFFu);
    int d   = (int)((r >> 16) & 0xFFFFu);
    int xid = (int)((r >> 32) & 0xFFFFu);
    float nrm = dinv[s] * dinv[d];          // self-loop s==d -> dinv^2, same formula
    int ld = d - n0;
    int p = loff[ld] + atomicAdd(&lcur[ld], 1);
    rec[p] = ((u64)f2bf(nrm) << 48) | ((u64)(unsigned)xid << 16) | (u64)(unsigned)s;
  }
}

// agg1[d][f] = sum over CSR[d] of norm * embb[xid][f]
// wave-per-node, 4 edges per gather instruction: lane = (eslot 0..3, fgrp 0..15),
// dwordx4 (8 feats) per lane; 16-edge leading loop for MLP depth;
// cross-eslot shuffle reduce at node end.
__global__ __launch_bounds__(256) void agg1w_kernel(const int* __restrict__ off,
    const u64* __restrict__ rec, const uint4* __restrict__ emb16,
    uint4* __restrict__ agg16) {
  int lane = threadIdx.x & 63;
  int node = __builtin_amdgcn_readfirstlane(blockIdx.x * 4 + (threadIdx.x >> 6));
  int beg = off[node], end = off[node + 1];
  int eslot = lane >> 4, fgrp = lane & 15;
  float a[8];
  #pragma unroll
  for (int j = 0; j < 8; ++j) a[j] = 0.f;
  int i = beg;
  for (; i + 16 <= end; i += 16) {        // 4 groups of 4 edges in flight
    u64 r0 = rec[i + eslot];
    u64 r1 = rec[i + 4 + eslot];
    u64 r2 = rec[i + 8 + eslot];
    u64 r3 = rec[i + 12 + eslot];
    uint4 v0 = emb16[rec_xid(r0) * 16 + fgrp];
    uint4 v1 = emb16[rec_xid(r1) * 16 + fgrp];
    uint4 v2 = emb16[rec_xid(r2) * 16 + fgrp];
    uint4 v3 = emb16[rec_xid(r3) * 16 + fgrp];
    float n0 = rec_nrm(r0), n1 = rec_nrm(r1), n2 = rec_nrm(r2), n3 = rec_nrm(r3);
    a[0] += n0 * bflo(v0.x); a[1] += n0 * bfhi(v0.x);
    a[2] += n0 * bflo(v0.y); a[3] += n0 * bfhi(v0.y);
    a[4] += n0 * bflo(v0.z); a[5] += n0 * bfhi(v0.z);
    a[6] += n0 * bflo(v0.w); a[7] += n0 * bfhi(v0.w);
    a[0] += n1 * bflo(v1.x); a[1] += n1 * bfhi(v1.x);
    a[2] += n1 * bflo(v1.y); a[3] += n1 * bfhi(v1.y);
    a[4] += n1 * bflo(v1.z); a[5] += n1 * bfhi(v1.z);
    a[6] += n1 * bflo(v1.w); a[7] += n1 * bfhi(v1.w);
    a[0] += n2 * bflo(v2.x); a[1] += n2 * bfhi(v2.x);
    a[2] += n2 * bflo(v2.y); a[3] += n2 * bfhi(v2.y);
    a[4] += n2 * bflo(v2.z); a[5] += n2 * bfhi(v2.z);
    a[6] += n2 * bflo(v2.w); a[7] += n2 * bfhi(v2.w);
    a[0] += n3 * bflo(v3.x); a[1] += n3 * bfhi(v3.x);
    a[2] += n3 * bflo(v3.y); a[3] += n3 * bfhi(v3.y);
    a[4] += n3 * bflo(v3.z); a[5] += n3 * bfhi(v3.z);
    a[6] += n3 * bflo(v3.w); a[7] += n3 * bfhi(v3.w);
  }
  for (; i + 8 <= end; i += 8) {          // 2 groups of 4 edges
    u64 rA = rec[i + eslot];
    u64 rB = rec[i + 4 + eslot];
    uint4 vA = emb16[rec_xid(rA) * 16 + fgrp];
    uint4 vB = emb16[rec_xid(rB) * 16 + fgrp];
    float nA = rec_nrm(rA), nB = rec_nrm(rB);
    a[0] += nA * bflo(vA.x); a[1] += nA * bfhi(vA.x);
    a[2] += nA * bflo(vA.y); a[3] += nA * bfhi(vA.y);
    a[4] += nA * bflo(vA.z); a[5] += nA * bfhi(vA.z);
    a[6] += nA * bflo(vA.w); a[7] += nA * bfhi(vA.w);
    a[0] += nB * bflo(vB.x); a[1] += nB * bfhi(vB.x);
    a[2] += nB * bflo(vB.y); a[3] += nB * bfhi(vB.y);
    a[4] += nB * bflo(vB.z); a[5] += nB * bfhi(vB.z);
    a[6] += nB * bflo(vB.w); a[7] += nB * bfhi(vB.w);
  }
  for (; i < end; i += 4) {               // tail groups (masked)
    int idx = i + eslot;
    bool val = idx < end;
    u64 r = rec[val ? idx : (end - 1)];
    uint4 v = emb16[rec_xid(r) * 16 + fgrp];
    float n = val ? rec_nrm(r) : 0.f;
    a[0] += n * bflo(v.x); a[1] += n * bfhi(v.x);
    a[2] += n * bflo(v.y); a[3] += n * bfhi(v.y);
    a[4] += n * bflo(v.z); a[5] += n * bfhi(v.z);
    a[6] += n * bflo(v.w); a[7] += n * bfhi(v.w);
  }
  #pragma unroll
  for (int j = 0; j < 8; ++j) {           // reduce across eslots (lanes ^16, ^32)
    a[j] += __shfl_xor(a[j], 16);
    a[j] += __shfl_xor(a[j], 32);
  }
  if (lane < 16) {
    uint4 o;
    o.x = pk2(a[0], a[1]); o.y = pk2(a[2], a[3]);
    o.z = pk2(a[4], a[5]); o.w = pk2(a[6], a[7]);
    agg16[(size_t)node * 16 + fgrp] = o;
  }
}

// FUSED: h2b = bf16( relu(agg1@W1+b1) @ W2 ).  64-row tile, y1 lives in LDS only.
__global__ __launch_bounds__(256) void gemm12_mfma(const unsigned short* __restrict__ agg1,
    const bh8* __restrict__ w1f, const float* __restrict__ b1,
    const bh8* __restrict__ w2f, unsigned short* __restrict__ h2b) {
  __shared__ char raw[32768];   // phase1: agg1 tile 64x128 bf16 in [0:16K]; phase2: y1 tile 64x256 bf16
  int t = threadIdx.x, lane = t & 63, wave = t >> 6;
  int row0 = blockIdx.x * 64;
  #pragma unroll
  for (int k = 0; k < 4; ++k) {
    int idx = k * 256 + t;            // 16B chunk id, tile = 1024 chunks
    int r = idx >> 4, cc = idx & 15;
    int4 v = make_int4(0, 0, 0, 0);
    if (row0 + r < N_NODES)
      v = *(const int4*)((const char*)agg1 + (size_t)(row0 + r) * 256 + cc * 16);
    *(int4*)(raw + ((r * 256 + cc * 16) ^ ((r & 15) << 4))) = v;
  }
  bh8 bf1[4][4];
  #pragma unroll
  for (int cf = 0; cf < 4; ++cf)
    #pragma unroll
    for (int ks = 0; ks < 4; ++ks)
      bf1[cf][ks] = w1f[(ks * 16 + wave * 4 + cf) * 64 + lane];
  f4 acc[4][4];
  #pragma unroll
  for (int rf = 0; rf < 4; ++rf)
    #pragma unroll
    for (int cf = 0; cf < 4; ++cf)
      acc[rf][cf] = (f4){0.f, 0.f, 0.f, 0.f};
  __syncthreads();
  #pragma unroll
  for (int ks = 0; ks < 4; ++ks) {
    bh8 a[4];
    #pragma unroll
    for (int rf = 0; rf < 4; ++rf) {
      int r = rf * 16 + (lane & 15);
      int byte = (r * 256 + ks * 64 + ((lane >> 4) << 4)) ^ ((r & 15) << 4);
      a[rf] = *(const bh8*)(raw + byte);
    }
    #pragma unroll
    for (int rf = 0; rf < 4; ++rf)
      #pragma unroll
      for (int cf = 0; cf < 4; ++cf)
        acc[rf][cf] = __builtin_amdgcn_mfma_f32_16x16x32_bf16(a[rf], bf1[cf][ks], acc[rf][cf], 0, 0, 0);
  }
  __syncthreads();    // all agg1-tile reads complete before overwrite
  #pragma unroll
  for (int cf = 0; cf < 4; ++cf) {
    int col = wave * 64 + cf * 16 + (lane & 15);
    float bias = b1[col];
    #pragma unroll
    for (int rf = 0; rf < 4; ++rf)
      #pragma unroll
      for (int j = 0; j < 4; ++j) {
        int r = rf * 16 + ((lane >> 4) << 2) + j;
        unsigned short v = f2bf(fmaxf(acc[rf][cf][j] + bias, 0.f));
        *(unsigned short*)(raw + ((r * 512 + col * 2) ^ ((r & 15) << 4))) = v;
      }
  }
  bh8 bf2[3][8];
  #pragma unroll
  for (int cf = 0; cf < 3; ++cf)
    #pragma unroll
    for (int ks = 0; ks < 8; ++ks)
      bf2[cf][ks] = w2f[(ks * 3 + cf) * 64 + lane];
  f4 acc2[3];
  #pragma unroll
  for (int cf = 0; cf < 3; ++cf) acc2[cf] = (f4){0.f, 0.f, 0.f, 0.f};
  __syncthreads();
  int r2 = wave * 16 + (lane & 15);
  #pragma unroll
  for (int ks = 0; ks < 8; ++ks) {
    int byte = (r2 * 512 + ks * 64 + ((lane >> 4) << 4)) ^ ((r2 & 15) << 4);
    bh8 a = *(const bh8*)(raw + byte);
    #pragma unroll
    for (int cf = 0; cf < 3; ++cf)
      acc2[cf] = __builtin_amdgcn_mfma_f32_16x16x32_bf16(a, bf2[cf][ks], acc2[cf], 0, 0, 0);
  }
  #pragma unroll
  for (int cf = 0; cf < 3; ++cf) {
    int col = cf * 16 + (lane & 15);
    #pragma unroll
    for (int j = 0; j < 4; ++j) {
      int rg = row0 + wave * 16 + ((lane >> 4) << 2) + j;
      if (rg < N_NODES)
        h2b[(size_t)rg * ODP + col] = f2bf(acc2[cf][j]);
    }
  }
}

// fused layer-2 aggregation + graph pooling.
// 10 edges per gather instruction: lane = (eslot 0..9, fgrp 0..5), dwordx4/lane;
// 20-edge (2-group) leading loop; 16 chunk-blocks per graph; LDS reduce.
__global__ __launch_bounds__(256) void pool2_kernel(const int* __restrict__ gstart,
    const int* __restrict__ off, const u64* __restrict__ rec,
    const unsigned short* __restrict__ h2b, const float* __restrict__ b2,
    float* __restrict__ out) {
  __shared__ float red[4][60][8];   // 30.7 KB
  int g = blockIdx.x >> 4, c = blockIdx.x & 15;
  int t = threadIdx.x, lane = t & 63, wv = t >> 6;
  int n0 = gstart[g], n1 = gstart[g + 1];
  int e0 = off[n0], e1 = off[n1];
  int len = e1 - e0;
  int c0 = e0 + ((len * c) >> 4);
  int c1 = e0 + ((len * (c + 1)) >> 4);
  int clen = c1 - c0;
  int w0 = c0 + ((clen * wv) >> 2);
  int w1 = c0 + ((clen * (wv + 1)) >> 2);
  bool live = lane < 60;
  int eslot = live ? lane / 6 : 0;      // 0..9
  int fgrp  = live ? lane - (lane / 6) * 6 : 0;   // 0..5 (feats fgrp*8..+7)
  float a[8];
  #pragma unroll
  for (int j = 0; j < 8; ++j) a[j] = 0.f;
  int i = w0;
  for (; i + 20 <= w1; i += 20) {       // 20 edges (2 groups) in flight
    u64 rA = rec[i + eslot];
    u64 rB = rec[i + 10 + eslot];
    uint4 vA = *(const uint4*)(h2b + (size_t)rec_src(rA) * ODP + fgrp * 8);
    uint4 vB = *(const uint4*)(h2b + (size_t)rec_src(rB) * ODP + fgrp * 8);
    float nA = live ? rec_nrm(rA) : 0.f;
    float nB = live ? rec_nrm(rB) : 0.f;
    a[0] += nA * bflo(vA.x); a[1] += nA * bfhi(vA.x);
    a[2] += nA * bflo(vA.y); a[3] += nA * bfhi(vA.y);
    a[4] += nA * bflo(vA.z); a[5] += nA * bfhi(vA.z);
    a[6] += nA * bflo(vA.w); a[7] += nA * bfhi(vA.w);
    a[0] += nB * bflo(vB.x); a[1] += nB * bfhi(vB.x);
    a[2] += nB * bflo(vB.y); a[3] += nB * bfhi(vB.y);
    a[4] += nB * bflo(vB.z); a[5] += nB * bfhi(vB.z);
    a[6] += nB * bflo(vB.w); a[7] += nB * bfhi(vB.w);
  }
  for (; i + 10 <= w1; i += 10) {
    u64 r = rec[i + eslot];
    uint4 v = *(const uint4*)(h2b + (size_t)rec_src(r) * ODP + fgrp * 8);
    float n = live ? rec_nrm(r) : 0.f;
    a[0] += n * bflo(v.x); a[1] += n * bfhi(v.x);
    a[2] += n * bflo(v.y); a[3] += n * bfhi(v.y);
    a[4] += n * bflo(v.z); a[5] += n * bfhi(v.z);
    a[6] += n * bflo(v.w); a[7] += n * bfhi(v.w);
  }
  if (i < w1) {                         // one masked tail group
    int idx = i + eslot;
    bool val = live && idx < w1;
    u64 r = rec[val ? idx : w0];
    uint4 v = *(const uint4*)(h2b + (size_t)rec_src(r) * ODP + fgrp * 8);
    float n = val ? rec_nrm(r) : 0.f;
    a[0] += n * bflo(v.x); a[1] += n * bfhi(v.x);
    a[2] += n * bflo(v.y); a[3] += n * bfhi(v.y);
    a[4] += n * bflo(v.z); a[5] += n * bfhi(v.z);
    a[6] += n * bflo(v.w); a[7] += n * bfhi(v.w);
  }
  if (live) {
    #pragma unroll
    for (int j = 0; j < 8; ++j) red[wv][lane][j] = a[j];
  }
  __syncthreads();
  if (t < 48) {                         // feature f = t
    int fg = t >> 3, j = t & 7;
    float s = 0.f;
    #pragma unroll
    for (int w = 0; w < 4; ++w)
      #pragma unroll
      for (int e = 0; e < 10; ++e)
        s += red[w][e * 6 + fg][j];
    if (t < OD) {
      if (c == 0) s += (float)(n1 - n0) * b2[t];
      unsafeAtomicAdd(&out[g * OD + t], s);
    }
  }
}

extern "C" void kernel_launch(void* const* d_in, const int* in_sizes, int n_in,
                              void* d_out, int out_size, void* d_ws, size_t ws_size,
                              hipStream_t stream) {
  const int*   x_ids = (const int*)d_in[0];
  const int*   ei    = (const int*)d_in[1];
  const int*   batch = (const int*)d_in[2];
  const float* emb   = (const float*)d_in[3];
  const float* W1    = (const float*)d_in[4];
  const float* b1    = (const float*)d_in[5];
  const float* W2    = (const float*)d_in[6];
  const float* b2    = (const float*)d_in[7];
  float* out = (float*)d_out;
  char* ws = (char*)d_ws;

  // workspace layout (bytes)
  int*            curB   = (int*)           (ws + 0);          // 512 B bucket cursors
  float*          dinv   = (float*)         (ws + 4096);       // 200 KB
  int*            off    = (int*)           (ws + 208896);     // 200 KB (+4)
  int*            gstart = (int*)           (ws + 413696);     // 2052 B
  unsigned short* embb   = (unsigned short*)(ws + 1048576);    // 343 KB bf16 emb
  unsigned short* w1f    = (unsigned short*)(ws + 1441792);    // 64 KB frag-linear
  unsigned short* w2f    = (unsigned short*)(ws + 1507328);    // 24 KB frag-linear
  u64*            rec    = (u64*)           (ws + 2097152);    // 6.8 MB final CSR records
  u64*            stage  = (u64*)           (ws + 9437184);    // 8.4 MB bucket staging
  unsigned short* agg1   = (unsigned short*)(ws + 18874368);   // 12.8 MB bf16
  unsigned short* h2b    = (unsigned short*)(ws + 33554432);   // 4.8 MB

  init_kernel <<<908, 256, 0, stream>>>(emb, W1, W2, batch, embb, w1f, w2f,
                                        (float4*)curB, (float4*)out, gstart);
  passA_kernel<<<208, 256, 0, stream>>>(ei, x_ids, curB, stage);
  countscan_kernel<<<NB, 256, 0, stream>>>(curB, stage, off, dinv);
  passB_kernel<<<NB,  256, 0, stream>>>(curB, stage, off, dinv, rec);

  agg1w_kernel<<<12500, 256, 0, stream>>>(off, rec, (const uint4*)embb, (uint4*)agg1);
  gemm12_mfma <<<782,   256, 0, stream>>>(agg1, (const bh8*)w1f, b1, (const bh8*)w2f, h2b);
  pool2_kernel<<<8192,  256, 0, stream>>>(gstart, off, rec, h2b, b2, out);
}